// Round 4
// baseline (264.403 us; speedup 1.0000x reference)
//
#include <hip/hip_runtime.h>

// VQ-VAE quantizer — round 13: INVERTED decomposition (lane = code).
// Inputs fp32: z_e [32,64,64,64], codebook [512,64].
// Output fp32: z_q [8388608] ++ indices-as-float [131072].
//
// Reference (np, fp32): d = rn( rn(s1 + s2[k]) - 2*M32[k] ), argmin ties->lowest.
//   s1 = np.sum(z**2,axis=1):  square->round, pairwise-8 accumulators, no fma.
//   s2 = np.sum(cb**2,axis=1): same.
//   M32 = sgemm(z_flat, cb^T): sequential-c single-accumulator fmaf chain.
// The fp32 grid must be replicated EXACTLY (R8). All formulas preserved.
//
// R9-R12 post-mortem: three structural changes to z's storage (ILP, asm pin,
// LDS) were ALL neutral at ~210us. The invariant across them: every wave
// streams the whole 128KB codebook through SGPRs (1KB/iter, ~64 SGPRs of
// buffer -> load/use/reload batches, each exposing K$/L2 latency at only
// 2 waves/SIMD). Fix: flip the decomposition. Lane <- code: each lane holds
// its codebook row in 64 VGPRs for the WHOLE kernel (loaded once); z becomes
// the streamed operand, and per sample z is wave-uniform -> scalar pipe
// (4x s_load_dwordx16), VALU ~= pure fma. Per-sample argmin across lanes:
// fminf butterfly + ballot + ffs -> lowest lane = lowest k (exact tie-break,
// d bit-identical per (n,k)). Cross-wave merge in LDS, ascending w, strict <.
//
// z channels are strided 16KB -> kernel A transposes z into row-contiguous
// z_t[n][64] staged IN THE OUTPUT z_q region (33.5MB, exact fit) + s1[n] in
// the indices region; kernel B consumes its block-local slice (all reads
// complete before barriers) then overwrites both slices with final output.

typedef __attribute__((ext_vector_type(4))) float fl4;

// ---------- kernel A: z -> z_t[n][64] (row-contiguous) + s1[n] ----------
__global__ __launch_bounds__(256)
void vq13a(const float* __restrict__ z, float* __restrict__ ow)
{
    __shared__ float zl[256][65];              // +1 dword pad: conflict-free
    const int tid = threadIdx.x;
    const int n0  = blockIdx.x << 8;           // 512 blocks x 256 samples
    const int n   = n0 + tid;
    const size_t base = (size_t)(n >> 12) * 262144 + (size_t)(n & 4095);

    float p[8];
    #pragma unroll
    for (int c = 0; c < 64; ++c) {
        const float v = z[base + (size_t)c * 4096];   // coalesced across tid
        zl[tid][c] = v;
        const float sq = __fmul_rn(v, v);             // np: z**2 rounds first
        if (c < 8) p[c] = sq;                         // m = 0
        else       p[c & 7] = __fadd_rn(p[c & 7], sq);
    }
    const float s1 = __fadd_rn(__fadd_rn(__fadd_rn(p[0],p[1]),__fadd_rn(p[2],p[3])),
                               __fadd_rn(__fadd_rn(p[4],p[5]),__fadd_rn(p[6],p[7])));
    ow[8388608 + n] = s1;                             // s1 -> indices region
    __syncthreads();

    // coalesced tile write: fl4 f = j*256+tid -> sample f>>4, chans (f&15)*4
    float* zt = ow + (size_t)n0 * 64;
    #pragma unroll
    for (int j = 0; j < 16; ++j) {
        const int f  = j * 256 + tid;
        const int nl = f >> 4, c0 = (f & 15) << 2;
        fl4 v;
        #pragma unroll
        for (int e = 0; e < 4; ++e) v[e] = zl[nl][c0 + e];  // <=2-way: free
        *(fl4*)(zt + ((size_t)f << 2)) = v;
    }
}

// ---------- kernel B: lane=code argmin + gather ----------
#define CBE(i) cbv[(i) >> 2][(i) & 3]

__global__ __launch_bounds__(512, 4)          // force <=128 VGPR: 4 waves/SIMD
void vq13b(const float* __restrict__ cb,
           const float* __restrict__ zt,      // == ow (z_q region)
           const float* __restrict__ s1g,     // == ow + 8388608
           float* __restrict__ ow)
{
    __shared__ float s1l[128];
    __shared__ float cdl[8][128];             // per-wave candidate d
    __shared__ int   ckl[8][128];             // per-wave candidate k
    __shared__ int   ifin[128];

    const int tid  = threadIdx.x;
    const int w    = tid >> 6;                // wave 0..7
    const int lane = tid & 63;
    const int n0   = blockIdx.x << 7;         // 1024 blocks x 128 samples
    const int k    = (w << 6) + lane;         // this lane's code

    // codebook row -> 64 VGPRs, resident for the whole kernel
    fl4 cbv[16];
    {
        const fl4* rp = (const fl4*)(cb + ((size_t)k << 6));
        #pragma unroll
        for (int j = 0; j < 16; ++j) cbv[j] = rp[j];
    }
    // s2 for this lane's code: np order (square->round, pairwise-8, no fma)
    float s2k;
    {
        float q[8];
        #pragma unroll
        for (int j = 0; j < 8; ++j) q[j] = __fmul_rn(CBE(j), CBE(j));
        #pragma unroll
        for (int m = 1; m < 8; ++m)
            #pragma unroll
            for (int j = 0; j < 8; ++j) {
                const float v = CBE(m * 8 + j);
                q[j] = __fadd_rn(q[j], __fmul_rn(v, v));
            }
        s2k = __fadd_rn(__fadd_rn(__fadd_rn(q[0],q[1]),__fadd_rn(q[2],q[3])),
                        __fadd_rn(__fadd_rn(q[4],q[5]),__fadd_rn(q[6],q[7])));
    }

    if (tid < 128) s1l[tid] = s1g[n0 + tid];  // read BEFORE it's overwritten
    __syncthreads();

    // ---- sample loop: z row via scalar pipe, 64-fma chain per lane ----
    for (int s = 0; s < 128; ++s) {
        const float* zr = zt + ((size_t)(n0 + s) << 6);   // wave-uniform -> s_load
        float m = 0.0f;
        #pragma unroll
        for (int c = 0; c < 64; ++c)
            m = fmaf(zr[c], CBE(c), m);       // c-ascending single-acc: ref chain
        const float T = __fadd_rn(s1l[s], s2k);           // np: rn(s1+s2)
        const float d = __fsub_rn(T, 2.0f * m);           // np: rn(T-2M), 2M exact

        // wave argmin: value-min butterfly, then lowest lane among equals
        float dm = d;
        #pragma unroll
        for (int off = 1; off < 64; off <<= 1)
            dm = fminf(dm, __shfl_xor(dm, off, 64));
        const unsigned long long eq = __ballot(d == dm);
        if (lane == 0) {
            cdl[w][s] = dm;
            ckl[w][s] = (w << 6) + (__ffsll((long long)eq) - 1); // lowest k
        }
    }
    __syncthreads();                           // all zt/s1g reads complete

    // ---- cross-wave merge: ascending w, strict < => lowest k on ties ----
    if (tid < 128) {
        float bd = cdl[0][tid]; int bk = ckl[0][tid];
        #pragma unroll
        for (int ww = 1; ww < 8; ++ww) {
            const float dw = cdl[ww][tid];
            const int   kw = ckl[ww][tid];
            if (dw < bd) { bd = dw; bk = kw; }
        }
        ifin[tid] = bk;
        ow[8388608 + n0 + tid] = (float)bk;    // overwrite s1 slice (safe now)
    }
    __syncthreads();

    // ---- z_q gather: 128 samples x 64 floats, coalesced 16B stores ----
    float* ob = ow + ((size_t)n0 << 6);        // overwrite z_t slice (safe now)
    #pragma unroll
    for (int it = 0; it < 4; ++it) {
        const int o    = it * 2048 + (tid << 2);   // float offset [0, 8192)
        const int sloc = o >> 6;
        const int c0   = o & 63;
        const int idx  = ifin[sloc] & 511;
        const fl4 v = *(const fl4*)(cb + ((size_t)idx << 6) + c0);
        *(fl4*)(ob + o) = v;
    }
}

extern "C" void kernel_launch(void* const* d_in, const int* in_sizes, int n_in,
                              void* d_out, int out_size, void* d_ws, size_t ws_size,
                              hipStream_t stream) {
    const float* z  = (const float*)d_in[0];   // z_e fp32 [32,64,64,64]
    const float* cb = (const float*)d_in[1];   // codebook fp32 [512,64]
    float* out = (float*)d_out;                // fp32: z_q [8388608] ++ idx [131072]
    vq13a<<<512, 256, 0, stream>>>(z, out);
    vq13b<<<1024, 512, 0, stream>>>(cb, out, out + 8388608, out);
}